// Round 1
// baseline (3993.921 us; speedup 1.0000x reference)
//
#include <hip/hip_runtime.h>
#include <math.h>

#define B_    512
#define SQ_   49
#define SK_   50
#define DIMG_ 2048
#define DTXT_ 768
#define D_    512
#define H_    4
#define DH_   128

// output offsets (floats): score, attn_output, attn_weights, pi, pt
#define SCORE_OFF 0
#define AO_OFF    262144      // 512*512
#define AW_OFF    13107200    // + 512*49*512
#define PI_OFF    14361600    // + 512*49*50
#define PT_OFF    27206656    // + 512*49*512

static __device__ __forceinline__ float gelu_exact(float x) {
    return 0.5f * x * (1.0f + erff(x * 0.70710678118654752f));
}

// ---------------------------------------------------------------------------
// Generic tiled fp32 GEMM: C[M,N] = op(A)[M,K] @ B[K,N] (+bias) (+Ares)
// AMODE 0: A row-major (lda=K)
// AMODE 1: A[m,k] = image_features[b, k, s] with b=m/49, s=m%49 (transposed read)
// AMODE 2: gelu(A row-major)
// TRANSB : B stored as (N,K) row-major -> B[n*K+k]
// RES    : C += Ares[m*N + n]   (requires Ares row stride == N)
// M % 64 == 0, N % 64 == 0, K % 16 == 0 for all uses here.
// ---------------------------------------------------------------------------
template<int AMODE, bool RES, bool TRANSB>
__global__ __launch_bounds__(256) void gemm_kernel(
    const float* __restrict__ A, const float* __restrict__ Bm,
    const float* __restrict__ bias, const float* __restrict__ Ares,
    float* __restrict__ C, int M, int N, int K)
{
    const int BM = 64, BN = 64, BK = 16;
    __shared__ float As[BK][BM + 1];
    __shared__ float Bs[BK][BN + 1];
    const int tid = threadIdx.x;
    const int m0 = blockIdx.y * BM;
    const int n0 = blockIdx.x * BN;
    const int tc = tid & 15, tr = tid >> 4;
    float acc[4][4] = {};

    for (int k0 = 0; k0 < K; k0 += BK) {
        if (AMODE == 1) {
            #pragma unroll
            for (int i = 0; i < 4; ++i) {
                int idx = tid + i * 256;
                int m = idx & 63, kk = idx >> 6;
                int gm = m0 + m;
                int b = gm / SQ_, s = gm - b * SQ_;
                As[kk][m] = A[(size_t)b * (DIMG_ * SQ_) + (size_t)(k0 + kk) * SQ_ + s];
            }
        } else {
            #pragma unroll
            for (int i = 0; i < 4; ++i) {
                int idx = tid + i * 256;
                int m = idx >> 4, kk = idx & 15;
                float v = A[(size_t)(m0 + m) * K + k0 + kk];
                if (AMODE == 2) v = gelu_exact(v);
                As[kk][m] = v;
            }
        }
        if (TRANSB) {
            #pragma unroll
            for (int i = 0; i < 4; ++i) {
                int idx = tid + i * 256;
                int n = idx >> 4, kk = idx & 15;
                Bs[kk][n] = Bm[(size_t)(n0 + n) * K + k0 + kk];
            }
        } else {
            #pragma unroll
            for (int i = 0; i < 4; ++i) {
                int idx = tid + i * 256;
                int n = idx & 63, kk = idx >> 6;
                Bs[kk][n] = Bm[(size_t)(k0 + kk) * N + n0 + n];
            }
        }
        __syncthreads();
        #pragma unroll
        for (int kk = 0; kk < BK; ++kk) {
            float a4[4], b4[4];
            #pragma unroll
            for (int i = 0; i < 4; ++i) a4[i] = As[kk][tr * 4 + i];
            #pragma unroll
            for (int j = 0; j < 4; ++j) b4[j] = Bs[kk][tc * 4 + j];
            #pragma unroll
            for (int i = 0; i < 4; ++i)
                #pragma unroll
                for (int j = 0; j < 4; ++j)
                    acc[i][j] = fmaf(a4[i], b4[j], acc[i][j]);
        }
        __syncthreads();
    }

    #pragma unroll
    for (int i = 0; i < 4; ++i) {
        int gm = m0 + tr * 4 + i;
        #pragma unroll
        for (int j = 0; j < 4; ++j) {
            int gn = n0 + tc * 4 + j;
            float v = acc[i][j];
            if (bias) v += bias[gn];
            if (RES) v += Ares[(size_t)gm * N + gn];
            C[(size_t)gm * N + gn] = v;
        }
    }
}

// ---------------------------------------------------------------------------
// Row LayerNorm over D=512, one block (256 threads) per row.
// ---------------------------------------------------------------------------
__global__ __launch_bounds__(256) void ln_kernel(
    const float* __restrict__ h, const float* __restrict__ g,
    const float* __restrict__ be, float* __restrict__ out)
{
    __shared__ float red[256];
    const int row = blockIdx.x;
    const int tid = threadIdx.x;
    float v0 = h[(size_t)row * D_ + tid];
    float v1 = h[(size_t)row * D_ + 256 + tid];
    red[tid] = v0 + v1;
    __syncthreads();
    for (int s = 128; s > 0; s >>= 1) {
        if (tid < s) red[tid] += red[tid + s];
        __syncthreads();
    }
    float mu = red[0] * (1.0f / 512.0f);
    __syncthreads();
    float d0 = v0 - mu, d1 = v1 - mu;
    red[tid] = d0 * d0 + d1 * d1;
    __syncthreads();
    for (int s = 128; s > 0; s >>= 1) {
        if (tid < s) red[tid] += red[tid + s];
        __syncthreads();
    }
    float var = red[0] * (1.0f / 512.0f);
    float sc = rsqrtf(var + 1e-5f);
    out[(size_t)row * D_ + tid]       = g[tid] * d0 * sc + be[tid];
    out[(size_t)row * D_ + 256 + tid] = g[256 + tid] * d1 * sc + be[256 + tid];
}

// ---------------------------------------------------------------------------
// Fused attention per batch b: loops heads; q staged in LDS (pad 132 to kill
// bank conflicts), k/v read through L1; softmax + head-mean attn_weights in
// LDS (no atomics). o overwrites q's head slice (consumed into LDS first).
// ---------------------------------------------------------------------------
__global__ __launch_bounds__(256) void attn_kernel(
    const float* q, const float* k, const float* v,
    float* o, float* __restrict__ aw)
{
    __shared__ float qs[SQ_ * 132];
    __shared__ float sc[SQ_ * SK_];
    __shared__ float awl[SQ_ * SK_];
    const int b = blockIdx.x;
    const int tid = threadIdx.x;

    for (int e = tid; e < SQ_ * SK_; e += 256) awl[e] = 0.0f;

    for (int h = 0; h < H_; ++h) {
        // stage q[b,:,h] into LDS (float4)
        for (int e = tid; e < SQ_ * 32; e += 256) {
            int s = e >> 5, dv = e & 31;
            const float4* qg = (const float4*)(q + ((size_t)(b * SQ_ + s)) * D_ + h * DH_);
            *(float4*)(qs + s * 132 + 4 * dv) = qg[dv];
        }
        __syncthreads();
        // scores = q k^T / sqrt(DH)
        for (int e = tid; e < SQ_ * SK_; e += 256) {
            int qi = e / SK_, ki = e - qi * SK_;
            const float4* qa = (const float4*)(qs + qi * 132);
            const float4* ka = (const float4*)(k + ((size_t)(b * SK_ + ki)) * D_ + h * DH_);
            float sum = 0.f;
            #pragma unroll
            for (int t = 0; t < 32; ++t) {
                float4 a = qa[t], c = ka[t];
                sum += a.x * c.x + a.y * c.y + a.z * c.z + a.w * c.w;
            }
            sc[e] = sum * 0.08838834764831845f;  // 1/sqrt(128)
        }
        __syncthreads();
        // row softmax + accumulate head-mean
        if (tid < SQ_) {
            float mx = -1e30f;
            for (int ki = 0; ki < SK_; ++ki) mx = fmaxf(mx, sc[tid * SK_ + ki]);
            float sum = 0.f;
            for (int ki = 0; ki < SK_; ++ki) sum += expf(sc[tid * SK_ + ki] - mx);
            float inv = 1.0f / sum;
            for (int ki = 0; ki < SK_; ++ki) {
                float a = expf(sc[tid * SK_ + ki] - mx) * inv;
                sc[tid * SK_ + ki] = a;
                awl[tid * SK_ + ki] += 0.25f * a;
            }
        }
        __syncthreads();
        // o = a @ v  (float4 over d), write over q's head-h slice
        for (int e = tid; e < SQ_ * 32; e += 256) {
            int qi = e >> 5, dv = e & 31;
            const float4* vg = (const float4*)(v + ((size_t)(b * SK_)) * D_ + h * DH_);
            float4 sum = {0.f, 0.f, 0.f, 0.f};
            for (int ki = 0; ki < SK_; ++ki) {
                float a = sc[qi * SK_ + ki];
                float4 vv = vg[(size_t)ki * 128 + dv];
                sum.x = fmaf(a, vv.x, sum.x);
                sum.y = fmaf(a, vv.y, sum.y);
                sum.z = fmaf(a, vv.z, sum.z);
                sum.w = fmaf(a, vv.w, sum.w);
            }
            float4* og = (float4*)(o + ((size_t)(b * SQ_ + qi)) * D_ + h * DH_);
            og[dv] = sum;
        }
        __syncthreads();
    }
    for (int e = tid; e < SQ_ * SK_; e += 256)
        aw[(size_t)b * SQ_ * SK_ + e] = awl[e];
}

// ---------------------------------------------------------------------------
// avg_attn (mean over SQ) -> n1 = avg/||avg||; cls = pt[:,0,:] -> n2
// one block per b.
// ---------------------------------------------------------------------------
__global__ __launch_bounds__(256) void norm_kernel(
    const float* __restrict__ ao, const float* __restrict__ pt,
    float* __restrict__ n1, float* __restrict__ n2)
{
    __shared__ float red[256];
    const int b = blockIdx.x, tid = threadIdx.x;
    float s0 = 0.f, s1 = 0.f;
    for (int s = 0; s < SQ_; ++s) {
        s0 += ao[((size_t)(b * SQ_ + s)) * D_ + tid];
        s1 += ao[((size_t)(b * SQ_ + s)) * D_ + 256 + tid];
    }
    s0 *= (1.0f / 49.0f);
    s1 *= (1.0f / 49.0f);
    red[tid] = s0 * s0 + s1 * s1;
    __syncthreads();
    for (int st = 128; st > 0; st >>= 1) {
        if (tid < st) red[tid] += red[tid + st];
        __syncthreads();
    }
    float inv = rsqrtf(red[0]);
    __syncthreads();
    n1[(size_t)b * D_ + tid] = s0 * inv;
    n1[(size_t)b * D_ + 256 + tid] = s1 * inv;

    float c0 = pt[((size_t)(b * SK_)) * D_ + tid];
    float c1 = pt[((size_t)(b * SK_)) * D_ + 256 + tid];
    red[tid] = c0 * c0 + c1 * c1;
    __syncthreads();
    for (int st = 128; st > 0; st >>= 1) {
        if (tid < st) red[tid] += red[tid + st];
        __syncthreads();
    }
    float inv2 = rsqrtf(red[0]);
    n2[(size_t)b * D_ + tid] = c0 * inv2;
    n2[(size_t)b * D_ + 256 + tid] = c1 * inv2;
}

extern "C" void kernel_launch(void* const* d_in, const int* in_sizes, int n_in,
                              void* d_out, int out_size, void* d_ws, size_t ws_size,
                              hipStream_t stream)
{
    const float* img = (const float*)d_in[0];
    const float* txt = (const float*)d_in[1];
    const float* Wi1 = (const float*)d_in[2];  const float* bi1 = (const float*)d_in[3];
    const float* Wi2 = (const float*)d_in[4];  const float* bi2 = (const float*)d_in[5];
    const float* gi  = (const float*)d_in[6];  const float* bei = (const float*)d_in[7];
    const float* Wt1 = (const float*)d_in[8];  const float* bt1 = (const float*)d_in[9];
    const float* Wt2 = (const float*)d_in[10]; const float* bt2 = (const float*)d_in[11];
    const float* gt  = (const float*)d_in[12]; const float* bet = (const float*)d_in[13];
    const float* Wq  = (const float*)d_in[14]; const float* bq  = (const float*)d_in[15];
    const float* Wk  = (const float*)d_in[16]; const float* bk  = (const float*)d_in[17];
    const float* Wv  = (const float*)d_in[18]; const float* bv  = (const float*)d_in[19];
    const float* Wo  = (const float*)d_in[20]; const float* bo  = (const float*)d_in[21];
    float* out = (float*)d_out;

    // workspace: three 25600x512 fp32 buffers + n1/n2 (512x512 each) ~ 152 MiB
    float* bufA = (float*)d_ws;
    float* bufB = bufA + (size_t)25600 * 512;
    float* bufC = bufB + (size_t)25600 * 512;
    float* n1   = bufC + (size_t)25600 * 512;
    float* n2   = n1 + (size_t)512 * 512;

    const int MI = B_ * SQ_;  // 25088 (divisible by 64)
    const int MT = B_ * SK_;  // 25600 (divisible by 64)
    dim3 blk(256);

    // image proj head
    gemm_kernel<1, false, false><<<dim3(8, MI / 64), blk, 0, stream>>>(
        img, Wi1, bi1, nullptr, bufA, MI, D_, DIMG_);
    gemm_kernel<2, true, false><<<dim3(8, MI / 64), blk, 0, stream>>>(
        bufA, Wi2, bi2, bufA, bufB, MI, D_, D_);
    ln_kernel<<<dim3(MI), blk, 0, stream>>>(bufB, gi, bei, out + PI_OFF);

    // text proj head
    gemm_kernel<0, false, false><<<dim3(8, MT / 64), blk, 0, stream>>>(
        txt, Wt1, bt1, nullptr, bufA, MT, D_, DTXT_);
    gemm_kernel<2, true, false><<<dim3(8, MT / 64), blk, 0, stream>>>(
        bufA, Wt2, bt2, bufA, bufB, MT, D_, D_);
    ln_kernel<<<dim3(MT), blk, 0, stream>>>(bufB, gt, bet, out + PT_OFF);

    // q, k, v
    gemm_kernel<0, false, false><<<dim3(8, MI / 64), blk, 0, stream>>>(
        out + PI_OFF, Wq, bq, nullptr, bufA, MI, D_, D_);
    gemm_kernel<0, false, false><<<dim3(8, MT / 64), blk, 0, stream>>>(
        out + PT_OFF, Wk, bk, nullptr, bufB, MT, D_, D_);
    gemm_kernel<0, false, false><<<dim3(8, MT / 64), blk, 0, stream>>>(
        out + PT_OFF, Wv, bv, nullptr, bufC, MT, D_, D_);

    // attention (o overwrites bufA); attn_weights written directly
    attn_kernel<<<dim3(B_), blk, 0, stream>>>(bufA, bufB, bufC, bufA, out + AW_OFF);

    // attn_output = o @ Wo + bo
    gemm_kernel<0, false, false><<<dim3(8, MI / 64), blk, 0, stream>>>(
        bufA, Wo, bo, nullptr, out + AO_OFF, MI, D_, D_);

    // avg_attn/cls normalization, then score = n1 @ n2^T
    norm_kernel<<<dim3(B_), blk, 0, stream>>>(out + AO_OFF, out + PT_OFF, n1, n2);
    gemm_kernel<0, false, true><<<dim3(8, 8), blk, 0, stream>>>(
        n1, n2, nullptr, nullptr, out + SCORE_OFF, B_, B_, D_);
}

// Round 2
// 1262.620 us; speedup vs baseline: 3.1632x; 3.1632x over previous
//
#include <hip/hip_runtime.h>
#include <math.h>

#define B_    512
#define SQ_   49
#define SK_   50
#define DIMG_ 2048
#define DTXT_ 768
#define D_    512
#define H_    4
#define DH_   128

// output offsets (floats): score, attn_output, attn_weights, pi, pt
#define SCORE_OFF 0
#define AO_OFF    262144      // 512*512
#define AW_OFF    13107200    // + 512*49*512
#define PI_OFF    14361600    // + 512*49*50
#define PT_OFF    27206656    // + 512*49*512

typedef unsigned short bfbits;
typedef __attribute__((ext_vector_type(8))) short short8;
typedef __attribute__((ext_vector_type(4))) float floatx4;

static __device__ __forceinline__ bfbits f2bf(float f) {
    union { float f; unsigned u; } a; a.f = f;
    return (bfbits)((a.u + 0x7fffu + ((a.u >> 16) & 1u)) >> 16);
}
static __device__ __forceinline__ float bf2f(bfbits b) {
    union { unsigned u; float f; } a; a.u = ((unsigned)b) << 16;
    return a.f;
}
static __device__ __forceinline__ float gelu_exact(float x) {
    return 0.5f * x * (1.0f + erff(x * 0.70710678118654752f));
}

// ---------------------------------------------------------------------------
// Weight transpose+cast: W (K,N) fp32 -> Wt (N,K) bf16.  K,N % 32 == 0.
// ---------------------------------------------------------------------------
__global__ __launch_bounds__(256) void wcast_t(
    const float* __restrict__ W, bfbits* __restrict__ Wt, int K, int N)
{
    __shared__ float t[32][33];
    const int k0 = blockIdx.x * 32, n0 = blockIdx.y * 32;
    const int tx = threadIdx.x & 31, ty = threadIdx.x >> 5;  // 32 x 8
    #pragma unroll
    for (int i = 0; i < 32; i += 8)
        t[ty + i][tx] = W[(size_t)(k0 + ty + i) * N + n0 + tx];
    __syncthreads();
    #pragma unroll
    for (int i = 0; i < 32; i += 8)
        Wt[(size_t)(n0 + ty + i) * K + k0 + tx] = f2bf(t[tx][ty + i]);
}

// ---------------------------------------------------------------------------
// Image transpose+cast: img[b, k, s] fp32 -> A[(b*49+s), k] bf16 (K=2048)
// block = (k-tile of 64, b)
// ---------------------------------------------------------------------------
__global__ __launch_bounds__(256) void img_t(
    const float* __restrict__ img, bfbits* __restrict__ A)
{
    __shared__ float t[64][50];
    const int b = blockIdx.y, k0 = blockIdx.x * 64;
    const float* src = img + (size_t)b * (DIMG_ * SQ_) + (size_t)k0 * SQ_;
    for (int e = threadIdx.x; e < 64 * 49; e += 256) {
        int kl = e / 49, s = e - kl * 49;
        t[kl][s] = src[kl * 49 + s];
    }
    __syncthreads();
    bfbits* dst = A + (size_t)b * SQ_ * DIMG_ + k0;
    for (int e = threadIdx.x; e < 49 * 64; e += 256) {
        int s = e >> 6, kl = e & 63;
        dst[(size_t)s * DIMG_ + kl] = f2bf(t[kl][s]);
    }
}

// ---------------------------------------------------------------------------
// Flat fp32 -> bf16 cast, 4 elements/thread. n % 4 == 0.
// ---------------------------------------------------------------------------
__global__ __launch_bounds__(256) void cast4(
    const float* __restrict__ x, bfbits* __restrict__ y, int n4)
{
    int i = blockIdx.x * 256 + threadIdx.x;
    if (i < n4) {
        float4 v = ((const float4*)x)[i];
        ushort4 u;
        u.x = f2bf(v.x); u.y = f2bf(v.y); u.z = f2bf(v.z); u.w = f2bf(v.w);
        ((ushort4*)y)[i] = u;
    }
}

// ---------------------------------------------------------------------------
// bf16 MFMA GEMM: C[M,512] = A[M,K] @ Bt[512,K]^T + bias (+res fp32).
// 128x128 tile, BK=32, 4 waves (64x64 each, 4x4 MFMA grid), global_load_lds.
// M%128==0, K%32==0. res may alias Cf (element-wise read-then-write).
// GELU: Cb=gelu(v) bf16, Cf=v fp32. Else WBF: Cb=bf16(v). WF32: Cf=v.
// ---------------------------------------------------------------------------
template<bool RES, bool GELU, bool WF32, bool WBF>
__global__ __launch_bounds__(256) void gemm_bf16(
    const bfbits* __restrict__ A, const bfbits* __restrict__ Bt,
    const float* __restrict__ bias, const float* res,
    float* Cf, bfbits* __restrict__ Cb, int M, int K)
{
    constexpr int N = 512;
    __shared__ __attribute__((aligned(16))) bfbits As[128 * 32];
    __shared__ __attribute__((aligned(16))) bfbits Bs[128 * 32];
    const int tid  = threadIdx.x;
    const int wave = tid >> 6, lane = tid & 63;
    const int m0 = blockIdx.y * 128, n0 = blockIdx.x * 128;
    const int wm = (wave >> 1) * 64, wn = (wave & 1) * 64;
    const int lr = lane & 15, quad = lane >> 4;

    floatx4 acc[4][4];
    #pragma unroll
    for (int i = 0; i < 4; ++i)
        #pragma unroll
        for (int j = 0; j < 4; ++j) acc[i][j] = 0.0f;

    // per-lane source row/col offset for staging (chunk c: rows c*16+(lane>>2))
    const int srow = lane >> 2;            // 0..15
    const int skof = (lane & 3) * 8;       // 0,8,16,24

    for (int k0 = 0; k0 < K; k0 += 32) {
        #pragma unroll
        for (int i = 0; i < 2; ++i) {
            const int c = wave * 2 + i;                 // chunk 0..7, uniform in wave
            const int row = c * 16 + srow;
            const bfbits* ga = A + (size_t)(m0 + row) * K + k0 + skof;
            const bfbits* gb = Bt + (size_t)(n0 + row) * K + k0 + skof;
            __builtin_amdgcn_global_load_lds(
                (const __attribute__((address_space(1))) void*)ga,
                (__attribute__((address_space(3))) void*)(As + c * 512), 16, 0, 0);
            __builtin_amdgcn_global_load_lds(
                (const __attribute__((address_space(1))) void*)gb,
                (__attribute__((address_space(3))) void*)(Bs + c * 512), 16, 0, 0);
        }
        __syncthreads();

        short8 af[4], bfv[4];
        #pragma unroll
        for (int i = 0; i < 4; ++i) {
            af[i]  = *(const short8*)(As + (wm + i * 16 + lr) * 32 + quad * 8);
            bfv[i] = *(const short8*)(Bs + (wn + i * 16 + lr) * 32 + quad * 8);
        }
        #pragma unroll
        for (int i = 0; i < 4; ++i)
            #pragma unroll
            for (int j = 0; j < 4; ++j)
                acc[i][j] = __builtin_amdgcn_mfma_f32_16x16x32_bf16(
                    af[i], bfv[j], acc[i][j], 0, 0, 0);
        __syncthreads();
    }

    #pragma unroll
    for (int i = 0; i < 4; ++i) {
        #pragma unroll
        for (int j = 0; j < 4; ++j) {
            const int gc = n0 + wn + j * 16 + lr;
            const float bv = bias[gc];
            #pragma unroll
            for (int r = 0; r < 4; ++r) {
                const int gm = m0 + wm + i * 16 + quad * 4 + r;
                float v = acc[i][j][r] + bv;
                if (RES) v += res[(size_t)gm * N + gc];
                if (WF32) Cf[(size_t)gm * N + gc] = v;
                if (GELU) Cb[(size_t)gm * N + gc] = f2bf(gelu_exact(v));
                else if (WBF) Cb[(size_t)gm * N + gc] = f2bf(v);
            }
        }
    }
}

// ---------------------------------------------------------------------------
// Row LayerNorm over D=512; writes fp32 + bf16 copies.
// ---------------------------------------------------------------------------
__global__ __launch_bounds__(256) void ln2_kernel(
    const float* __restrict__ h, const float* __restrict__ g,
    const float* __restrict__ be, float* __restrict__ outf,
    bfbits* __restrict__ outb)
{
    __shared__ float red[256];
    const int row = blockIdx.x;
    const int tid = threadIdx.x;
    float v0 = h[(size_t)row * D_ + tid];
    float v1 = h[(size_t)row * D_ + 256 + tid];
    red[tid] = v0 + v1;
    __syncthreads();
    for (int s = 128; s > 0; s >>= 1) {
        if (tid < s) red[tid] += red[tid + s];
        __syncthreads();
    }
    float mu = red[0] * (1.0f / 512.0f);
    __syncthreads();
    float d0 = v0 - mu, d1 = v1 - mu;
    red[tid] = d0 * d0 + d1 * d1;
    __syncthreads();
    for (int s = 128; s > 0; s >>= 1) {
        if (tid < s) red[tid] += red[tid + s];
        __syncthreads();
    }
    float var = red[0] * (1.0f / 512.0f);
    float sc = rsqrtf(var + 1e-5f);
    float o0 = g[tid] * d0 * sc + be[tid];
    float o1 = g[256 + tid] * d1 * sc + be[256 + tid];
    outf[(size_t)row * D_ + tid]       = o0;
    outf[(size_t)row * D_ + 256 + tid] = o1;
    outb[(size_t)row * D_ + tid]       = f2bf(o0);
    outb[(size_t)row * D_ + 256 + tid] = f2bf(o1);
}

// ---------------------------------------------------------------------------
// Fused attention per batch b over bf16 q/k/v; fp32 math; writes bf16 o + aw.
// ---------------------------------------------------------------------------
__global__ __launch_bounds__(256) void attn_kernel(
    const bfbits* __restrict__ q, const bfbits* __restrict__ k,
    const bfbits* __restrict__ v, bfbits* __restrict__ o,
    float* __restrict__ aw)
{
    __shared__ float qs[SQ_ * 132];
    __shared__ float sc[SQ_ * SK_];
    __shared__ float awl[SQ_ * SK_];
    const int b = blockIdx.x;
    const int tid = threadIdx.x;

    for (int e = tid; e < SQ_ * SK_; e += 256) awl[e] = 0.0f;

    for (int h = 0; h < H_; ++h) {
        for (int e = tid; e < SQ_ * 32; e += 256) {
            int s = e >> 5, dv = e & 31;
            ushort4 u = *(const ushort4*)(q + ((size_t)(b * SQ_ + s)) * D_ + h * DH_ + dv * 4);
            float* dst = qs + s * 132 + dv * 4;
            dst[0] = bf2f(u.x); dst[1] = bf2f(u.y);
            dst[2] = bf2f(u.z); dst[3] = bf2f(u.w);
        }
        __syncthreads();
        for (int e = tid; e < SQ_ * SK_; e += 256) {
            int qi = e / SK_, ki = e - qi * SK_;
            const ushort4* ka = (const ushort4*)(k + ((size_t)(b * SK_ + ki)) * D_ + h * DH_);
            const float* qa = qs + qi * 132;
            float sum = 0.f;
            #pragma unroll
            for (int t = 0; t < 32; ++t) {
                ushort4 u = ka[t];
                sum += qa[4 * t]     * bf2f(u.x) + qa[4 * t + 1] * bf2f(u.y)
                     + qa[4 * t + 2] * bf2f(u.z) + qa[4 * t + 3] * bf2f(u.w);
            }
            sc[e] = sum * 0.08838834764831845f;  // 1/sqrt(128)
        }
        __syncthreads();
        if (tid < SQ_) {
            float mx = -1e30f;
            for (int ki = 0; ki < SK_; ++ki) mx = fmaxf(mx, sc[tid * SK_ + ki]);
            float sum = 0.f;
            for (int ki = 0; ki < SK_; ++ki) sum += expf(sc[tid * SK_ + ki] - mx);
            float inv = 1.0f / sum;
            for (int ki = 0; ki < SK_; ++ki) {
                float a = expf(sc[tid * SK_ + ki] - mx) * inv;
                sc[tid * SK_ + ki] = a;
                awl[tid * SK_ + ki] += 0.25f * a;
            }
        }
        __syncthreads();
        for (int e = tid; e < SQ_ * 32; e += 256) {
            int qi = e >> 5, dv = e & 31;
            const bfbits* vg = v + ((size_t)(b * SK_)) * D_ + h * DH_ + dv * 4;
            float4 sum = {0.f, 0.f, 0.f, 0.f};
            for (int ki = 0; ki < SK_; ++ki) {
                float a = sc[qi * SK_ + ki];
                ushort4 u = *(const ushort4*)(vg + (size_t)ki * D_);
                sum.x = fmaf(a, bf2f(u.x), sum.x);
                sum.y = fmaf(a, bf2f(u.y), sum.y);
                sum.z = fmaf(a, bf2f(u.z), sum.z);
                sum.w = fmaf(a, bf2f(u.w), sum.w);
            }
            ushort4 ou;
            ou.x = f2bf(sum.x); ou.y = f2bf(sum.y);
            ou.z = f2bf(sum.z); ou.w = f2bf(sum.w);
            *(ushort4*)(o + ((size_t)(b * SQ_ + qi)) * D_ + h * DH_ + dv * 4) = ou;
        }
        __syncthreads();
    }
    for (int e = tid; e < SQ_ * SK_; e += 256)
        aw[(size_t)b * SQ_ * SK_ + e] = awl[e];
}

// ---------------------------------------------------------------------------
// avg_attn -> n1; cls -> n2 (fp32)
// ---------------------------------------------------------------------------
__global__ __launch_bounds__(256) void norm_kernel(
    const float* __restrict__ ao, const float* __restrict__ pt,
    float* __restrict__ n1, float* __restrict__ n2)
{
    __shared__ float red[256];
    const int b = blockIdx.x, tid = threadIdx.x;
    float s0 = 0.f, s1 = 0.f;
    for (int s = 0; s < SQ_; ++s) {
        s0 += ao[((size_t)(b * SQ_ + s)) * D_ + tid];
        s1 += ao[((size_t)(b * SQ_ + s)) * D_ + 256 + tid];
    }
    s0 *= (1.0f / 49.0f);
    s1 *= (1.0f / 49.0f);
    red[tid] = s0 * s0 + s1 * s1;
    __syncthreads();
    for (int st = 128; st > 0; st >>= 1) {
        if (tid < st) red[tid] += red[tid + st];
        __syncthreads();
    }
    float inv = rsqrtf(red[0]);
    __syncthreads();
    n1[(size_t)b * D_ + tid] = s0 * inv;
    n1[(size_t)b * D_ + 256 + tid] = s1 * inv;

    float c0 = pt[((size_t)(b * SK_)) * D_ + tid];
    float c1 = pt[((size_t)(b * SK_)) * D_ + 256 + tid];
    red[tid] = c0 * c0 + c1 * c1;
    __syncthreads();
    for (int st = 128; st > 0; st >>= 1) {
        if (tid < st) red[tid] += red[tid + st];
        __syncthreads();
    }
    float inv2 = rsqrtf(red[0]);
    n2[(size_t)b * D_ + tid] = c0 * inv2;
    n2[(size_t)b * D_ + 256 + tid] = c1 * inv2;
}

// ---------------------------------------------------------------------------
// fp32 score GEMM: C[512,512] = n1[512,512] @ n2[512,512]^T  (tiny)
// ---------------------------------------------------------------------------
__global__ __launch_bounds__(256) void score_gemm(
    const float* __restrict__ A, const float* __restrict__ Bm,
    float* __restrict__ C)
{
    const int BM = 64, BN = 64, BK = 16, Kt = 512, Nt = 512;
    __shared__ float As[BK][BM + 1];
    __shared__ float Bs[BK][BN + 1];
    const int tid = threadIdx.x;
    const int m0 = blockIdx.y * BM, n0 = blockIdx.x * BN;
    const int tc = tid & 15, tr = tid >> 4;
    float acc[4][4] = {};
    for (int k0 = 0; k0 < Kt; k0 += BK) {
        #pragma unroll
        for (int i = 0; i < 4; ++i) {
            int idx = tid + i * 256;
            int m = idx >> 4, kk = idx & 15;
            As[kk][m] = A[(size_t)(m0 + m) * Kt + k0 + kk];
            Bs[kk][m] = Bm[(size_t)(n0 + m) * Kt + k0 + kk];
        }
        __syncthreads();
        #pragma unroll
        for (int kk = 0; kk < BK; ++kk) {
            float a4[4], b4[4];
            #pragma unroll
            for (int i = 0; i < 4; ++i) a4[i] = As[kk][tr * 4 + i];
            #pragma unroll
            for (int j = 0; j < 4; ++j) b4[j] = Bs[kk][tc * 4 + j];
            #pragma unroll
            for (int i = 0; i < 4; ++i)
                #pragma unroll
                for (int j = 0; j < 4; ++j)
                    acc[i][j] = fmaf(a4[i], b4[j], acc[i][j]);
        }
        __syncthreads();
    }
    #pragma unroll
    for (int i = 0; i < 4; ++i)
        #pragma unroll
        for (int j = 0; j < 4; ++j)
            C[(size_t)(m0 + tr * 4 + i) * Nt + n0 + tc * 4 + j] = acc[i][j];
}

extern "C" void kernel_launch(void* const* d_in, const int* in_sizes, int n_in,
                              void* d_out, int out_size, void* d_ws, size_t ws_size,
                              hipStream_t stream)
{
    const float* img = (const float*)d_in[0];
    const float* txt = (const float*)d_in[1];
    const float* Wi1 = (const float*)d_in[2];  const float* bi1 = (const float*)d_in[3];
    const float* Wi2 = (const float*)d_in[4];  const float* bi2 = (const float*)d_in[5];
    const float* gi  = (const float*)d_in[6];  const float* bei = (const float*)d_in[7];
    const float* Wt1 = (const float*)d_in[8];  const float* bt1 = (const float*)d_in[9];
    const float* Wt2 = (const float*)d_in[10]; const float* bt2 = (const float*)d_in[11];
    const float* gt  = (const float*)d_in[12]; const float* bet = (const float*)d_in[13];
    const float* Wq  = (const float*)d_in[14]; const float* bq  = (const float*)d_in[15];
    const float* Wk  = (const float*)d_in[16]; const float* bk  = (const float*)d_in[17];
    const float* Wv  = (const float*)d_in[18]; const float* bv  = (const float*)d_in[19];
    const float* Wo  = (const float*)d_in[20]; const float* bo  = (const float*)d_in[21];
    float* out = (float*)d_out;

    // ---- workspace layout (~230 MiB) ----
    bfbits* Wi1T = (bfbits*)d_ws;                 // 2048*512
    bfbits* Wi2T = Wi1T + 1048576;                // 512*512
    bfbits* Wt1T = Wi2T + 262144;                 // 768*512
    bfbits* Wt2T = Wt1T + 393216;
    bfbits* WqT  = Wt2T + 262144;
    bfbits* WkT  = WqT  + 262144;
    bfbits* WvT  = WkT  + 262144;
    bfbits* WoT  = WvT  + 262144;
    bfbits* R1   = WoT  + 262144;                 // 51,380,224 bf16 elems
    bfbits* Aimg = R1;                            // 25088*2048
    bfbits* Atxt = R1;                            // 25600*768 (after img phase)
    bfbits* Qbf  = R1 + 20000000;                 // 25088*512
    bfbits* Kbf  = R1 + 33200000;                 // 25600*512
    float*  R2   = (float*)(R1 + 51380224);       // 13,107,200 floats (P/H)
    bfbits* Vbf  = (bfbits*)R2;                   // 25600*512 (after H dead)
    bfbits* R3   = (bfbits*)(R2 + 13107200);      // 13,107,200 bf16 (G / Obf)
    bfbits* Obf  = R3;
    bfbits* PiBf = R3 + 13107200;                 // 25088*512
    bfbits* PtBf = PiBf + 12845056;               // 25600*512
    float*  n1   = (float*)(PtBf + 13107200);
    float*  n2   = n1 + 262144;

    const int MI = B_ * SQ_;   // 25088
    const int MT = B_ * SK_;   // 25600
    dim3 blk(256);

    // weights -> transposed bf16
    wcast_t<<<dim3(DIMG_ / 32, D_ / 32), blk, 0, stream>>>(Wi1, Wi1T, DIMG_, D_);
    wcast_t<<<dim3(D_ / 32, D_ / 32),    blk, 0, stream>>>(Wi2, Wi2T, D_, D_);
    wcast_t<<<dim3(DTXT_ / 32, D_ / 32), blk, 0, stream>>>(Wt1, Wt1T, DTXT_, D_);
    wcast_t<<<dim3(D_ / 32, D_ / 32),    blk, 0, stream>>>(Wt2, Wt2T, D_, D_);
    wcast_t<<<dim3(D_ / 32, D_ / 32),    blk, 0, stream>>>(Wq, WqT, D_, D_);
    wcast_t<<<dim3(D_ / 32, D_ / 32),    blk, 0, stream>>>(Wk, WkT, D_, D_);
    wcast_t<<<dim3(D_ / 32, D_ / 32),    blk, 0, stream>>>(Wv, WvT, D_, D_);
    wcast_t<<<dim3(D_ / 32, D_ / 32),    blk, 0, stream>>>(Wo, WoT, D_, D_);

    // ---- image head ----
    img_t<<<dim3(DIMG_ / 64, B_), blk, 0, stream>>>(img, Aimg);
    gemm_bf16<false, true, true, true><<<dim3(4, MI / 128), blk, 0, stream>>>(
        Aimg, Wi1T, bi1, nullptr, R2, R3, MI, DIMG_);            // p fp32 + gelu bf16
    gemm_bf16<true, false, true, false><<<dim3(4, MI / 128), blk, 0, stream>>>(
        R3, Wi2T, bi2, R2, R2, nullptr, MI, D_);                 // h = g@W2+b2+p (in-place)
    ln2_kernel<<<dim3(MI), blk, 0, stream>>>(R2, gi, bei, out + PI_OFF, PiBf);

    // ---- text head ----
    cast4<<<dim3((MT * DTXT_ / 4 + 255) / 256), blk, 0, stream>>>(txt, Atxt, MT * DTXT_ / 4);
    gemm_bf16<false, true, true, true><<<dim3(4, MT / 128), blk, 0, stream>>>(
        Atxt, Wt1T, bt1, nullptr, R2, R3, MT, DTXT_);
    gemm_bf16<true, false, true, false><<<dim3(4, MT / 128), blk, 0, stream>>>(
        R3, Wt2T, bt2, R2, R2, nullptr, MT, D_);
    ln2_kernel<<<dim3(MT), blk, 0, stream>>>(R2, gt, bet, out + PT_OFF, PtBf);

    // ---- q, k, v (bf16 out) ----
    gemm_bf16<false, false, false, true><<<dim3(4, MI / 128), blk, 0, stream>>>(
        PiBf, WqT, bq, nullptr, nullptr, Qbf, MI, D_);
    gemm_bf16<false, false, false, true><<<dim3(4, MT / 128), blk, 0, stream>>>(
        PtBf, WkT, bk, nullptr, nullptr, Kbf, MT, D_);
    gemm_bf16<false, false, false, true><<<dim3(4, MT / 128), blk, 0, stream>>>(
        PtBf, WvT, bv, nullptr, nullptr, Vbf, MT, D_);

    // ---- attention ----
    attn_kernel<<<dim3(B_), blk, 0, stream>>>(Qbf, Kbf, Vbf, Obf, out + AW_OFF);

    // ---- output projection ----
    gemm_bf16<false, false, true, false><<<dim3(4, MI / 128), blk, 0, stream>>>(
        Obf, WoT, bo, nullptr, out + AO_OFF, nullptr, MI, D_);

    // ---- similarity score ----
    norm_kernel<<<dim3(B_), blk, 0, stream>>>(out + AO_OFF, out + PT_OFF, n1, n2);
    score_gemm<<<dim3(8, 8), blk, 0, stream>>>(n1, n2, out + SCORE_OFF);
}